// Round 14
// baseline (79.397 us; speedup 1.0000x reference)
//
#include <hip/hip_runtime.h>

#define POOL 100
#define PLEN 8
#define EMB 768
#define KEYD 768
#define BATCH 256
#define LD (PLEN*EMB)              // 6144
#define EK_FLOATS (BATCH*4*EMB)    // 786432
#define XB_FLOATS (BATCH*197*EMB)  // 38756352
#define LOSS_OFF (2*EK_FLOATS)     // 1572864
#define XB_OFF (LOSS_OFF+1)        // 1572865 (4B-aligned only!)
#define NGT 325                    // 25*26/2 triangular 4x4 gram tiles
#define NCOS (BATCH*25)            // 6400 cos units
#define NPREP (NGT+NCOS)           // 6725 prep units
#define N4 9689087                 // (XB_FLOATS-3)/4 float4 in bulk copy
#define TILE 2048                  // float4 per copy block (R9 layout)
#define NTILES 4731                // ceil(N4/TILE); tile 4730 partial
#define NSG 421                    // supergroups in kernel1
#define COPY_A (NSG*8)             // 3368 tiles in kernel1
#define COPY_B (NTILES-COPY_A)     // 1363 tiles in kernel2
#define GRID1 (NSG*24)             // 10104: rank<8 copy, rank>=8 prep
#define GRID2 (BATCH+COPY_B)       // 1619

typedef float v4f __attribute__((ext_vector_type(4)));
typedef v4f v4f_u __attribute__((aligned(4)));   // 4B-aligned float4 view (tail only)

// --- copy tile: lane-contiguous slots, 8 aligned dwordx4 NT loads in flight,
// 8 shfl_up stitches, one divergent lane-0 fixup, 8 NT stores.
// (R12->R14 single-variable A/B: plain -> nontemporal LOADS; NT stores kept.)
__device__ __forceinline__ void copy_tile(const float* __restrict__ xb,
                                          float* __restrict__ out, int tile) {
    const v4f* src4 = (const v4f*)xb;                // 16B aligned
    v4f* dst = (v4f*)(out + XB_OFF + 3);             // 16B aligned
    size_t base = (size_t)tile * TILE + threadIdx.x;
    int lane = threadIdx.x & 63;
    if (base + 7 * 256 < N4) {                       // full tile
        v4f v[8];
        #pragma unroll
        for (int k = 0; k < 8; ++k)
            v[k] = __builtin_nontemporal_load(&src4[base + (size_t)k * 256 + 1]);
        float pw[8];
        #pragma unroll
        for (int k = 0; k < 8; ++k) pw[k] = __shfl_up(v[k][3], 1, 64);
        if (lane == 0) {                             // one divergent region
            #pragma unroll
            for (int k = 0; k < 8; ++k) pw[k] = xb[4 * (base + (size_t)k * 256) + 3];
        }
        #pragma unroll
        for (int k = 0; k < 8; ++k) {
            v4f o = {pw[k], v[k][0], v[k][1], v[k][2]};
            __builtin_nontemporal_store(o, &dst[base + (size_t)k * 256]);
        }
    } else {                                         // tail tile: misaligned fallback
        const v4f_u* srcu = (const v4f_u*)(xb + 3);
        #pragma unroll
        for (int k = 0; k < 8; ++k) {
            size_t j = base + (size_t)k * 256;
            if (j < N4) dst[j] = srcu[j];
        }
    }
}

// 4x4 row-group gram tile: block computes G[4gy+i][4gx+j] for i,j in 0..3.
__device__ __forceinline__ void gram_tile(const float* __restrict__ p,
                                          double* __restrict__ G, int t) {
    int gx = (int)((sqrt(8.0 * t + 1.0) - 1.0) * 0.5);
    while ((gx + 1) * (gx + 2) / 2 <= t) ++gx;
    while (gx * (gx + 1) / 2 > t) --gx;
    int gy = t - gx * (gx + 1) / 2;
    const v4f* P4 = (const v4f*)p;
    double acc[16];
    #pragma unroll
    for (int i = 0; i < 16; ++i) acc[i] = 0.0;
    #pragma unroll
    for (int ch = 0; ch < 6; ++ch) {                 // 1536 float4 cols / 256 thr
        int col = ch * 256 + threadIdx.x;
        v4f ay[4], ax[4];
        #pragma unroll
        for (int i = 0; i < 4; ++i) ay[i] = P4[(size_t)(4*gy + i) * 1536 + col];
        #pragma unroll
        for (int j = 0; j < 4; ++j) ax[j] = P4[(size_t)(4*gx + j) * 1536 + col];
        #pragma unroll
        for (int i = 0; i < 4; ++i)
            #pragma unroll
            for (int j = 0; j < 4; ++j)
                acc[i*4+j] += (double)ay[i][0]*ax[j][0] + (double)ay[i][1]*ax[j][1]
                            + (double)ay[i][2]*ax[j][2] + (double)ay[i][3]*ax[j][3];
    }
    #pragma unroll
    for (int i = 0; i < 16; ++i)
        for (int off = 32; off > 0; off >>= 1)
            acc[i] += __shfl_down(acc[i], off, 64);
    __shared__ double sg[4][16];
    int lane = threadIdx.x & 63, w = threadIdx.x >> 6;
    if (lane == 0) {
        #pragma unroll
        for (int i = 0; i < 16; ++i) sg[w][i] = acc[i];
    }
    __syncthreads();
    if (threadIdx.x < 16) {
        double v = sg[0][threadIdx.x] + sg[1][threadIdx.x]
                 + sg[2][threadIdx.x] + sg[3][threadIdx.x];
        int i = threadIdx.x >> 2, j = threadIdx.x & 3;
        int r = 4*gy + i, c = 4*gx + j;
        G[r * POOL + c] = v;
        G[c * POOL + r] = v;
    }
}

// cos[b,k] = <xq[b],K[k]> / max(||K[k]||,1e-12), one wave per (b,k).
__device__ __forceinline__ void cos_unit(const float* __restrict__ xq,
                                         const float* __restrict__ K,
                                         double* __restrict__ cosm, int c) {
    int b = c / 25, kg = c % 25;
    int w = threadIdx.x >> 6, lane = threadIdx.x & 63;
    int k = kg * 4 + w;
    const v4f* kr = (const v4f*)(K + (size_t)k * KEYD);
    const v4f* xr = (const v4f*)(xq + (size_t)b * KEYD);
    double dot = 0.0, sq = 0.0;
    #pragma unroll
    for (int it = 0; it < 3; ++it) {
        v4f a = kr[it * 64 + lane];
        v4f x = xr[it * 64 + lane];
        dot += (double)a[0]*x[0] + (double)a[1]*x[1] + (double)a[2]*x[2] + (double)a[3]*x[3];
        sq  += (double)a[0]*a[0] + (double)a[1]*a[1] + (double)a[2]*a[2] + (double)a[3]*a[3];
    }
    for (int off = 32; off > 0; off >>= 1) {
        dot += __shfl_down(dot, off, 64);
        sq  += __shfl_down(sq,  off, 64);
    }
    if (lane == 0)
        cosm[(size_t)b * POOL + k] = dot / fmax(sqrt(sq), 1e-12);
}

// Kernel 1: XCD-safe interleave of copy chunk A with ALL prep work.
// Supergroup = 24 consecutive blocks: ranks 0-7 copy (one per XCD per group),
// ranks 8-23 prep. Prep hides under copy BW.
__global__ void k1(const float* __restrict__ p, const float* __restrict__ xq,
                   const float* __restrict__ K, const float* __restrict__ xb,
                   float* __restrict__ out, double* __restrict__ G,
                   double* __restrict__ cosm, double* __restrict__ lossAcc,
                   unsigned int* __restrict__ lossCnt) {
    int b = blockIdx.x;
    int g = b / 24, r = b % 24;
    if (r < 8) {                                     // copy lane
        int tile = g * 8 + r;                        // 0..COPY_A-1, exact fit
        if (tile == 0) {
            if (threadIdx.x == 64) { lossAcc[0] = 0.0; lossCnt[0] = 0u; }
            if (threadIdx.x == 65) {
                out[XB_OFF]     = xb[0];
                out[XB_OFF + 1] = xb[1];
                out[XB_OFF + 2] = xb[2];
                out[XB_OFF + XB_FLOATS - 1] = xb[XB_FLOATS - 1];
            }
        }
        copy_tile(xb, out, tile);
        return;
    }
    int u = g * 16 + (r - 8);                        // prep unit 0..6735
    if (u < NGT)        gram_tile(p, G, u);
    else if (u < NPREP) cos_unit(xq, K, cosm, u - NGT);
    // else: 11 pad blocks
}

// Kernel 2: blocks [0,BATCH) = per-b vq (hidden under copy); rest = copy chunk B.
__global__ void k2(const double* __restrict__ cosm, const double* __restrict__ G,
                   const float* __restrict__ p, const float* __restrict__ xb,
                   float* __restrict__ out, double* __restrict__ lossAcc,
                   unsigned int* __restrict__ lossCnt) {
    if (blockIdx.x >= BATCH) {
        copy_tile(xb, out, COPY_A + (int)(blockIdx.x - BATCH));
        return;
    }
    int b = blockIdx.x;
    __shared__ double sa[POOL], sm[POOL];
    __shared__ double sred[4];
    __shared__ int sidx;
    int lane = threadIdx.x & 63, w = threadIdx.x >> 6;

    double cv = (threadIdx.x < POOL) ? cosm[(size_t)b * POOL + threadIdx.x] : -1.0e300;
    double m = cv;                                   // block max
    for (int off = 32; off > 0; off >>= 1) m = fmax(m, __shfl_down(m, off, 64));
    if (lane == 0) sred[w] = m;
    __syncthreads();
    m = fmax(fmax(sred[0], sred[1]), fmax(sred[2], sred[3]));
    __syncthreads();
    double e = (threadIdx.x < POOL) ? exp(cv - m) : 0.0;
    double ssum = e;                                 // block sum
    for (int off = 32; off > 0; off >>= 1) ssum += __shfl_down(ssum, off, 64);
    if (lane == 0) sred[w] = ssum;
    __syncthreads();
    ssum = sred[0] + sred[1] + sred[2] + sred[3];
    __syncthreads();
    if (threadIdx.x < POOL) sa[threadIdx.x] = e / ssum;   // alpha
    __syncthreads();
    double c = 0.0, paterm = 0.0;
    if (threadIdx.x < POOL) {
        #pragma unroll 4
        for (int k = 0; k < POOL; ++k)
            c += sa[k] * G[k * POOL + threadIdx.x];       // coalesced over tid
        paterm = sa[threadIdx.x] * c;
        sm[threadIdx.x] = G[threadIdx.x * POOL + threadIdx.x] - 2.0 * c;
    }
    double pa = paterm;                               // pa_sq block sum
    for (int off = 32; off > 0; off >>= 1) pa += __shfl_down(pa, off, 64);
    if (lane == 0) sred[w] = pa;
    __syncthreads();                                  // also fences sm[]
    pa = sred[0] + sred[1] + sred[2] + sred[3];
    if (threadIdx.x == 0) {
        int best = 0; double bm = sm[0];
        for (int k = 1; k < POOL; ++k)
            if (sm[k] < bm) { bm = sm[k]; best = k; }     // first-index tiebreak = np.argmin
        sidx = best;
        double dterm = pa + bm;    // = pa_sq - 2*cross[idx] + pp_sq[idx]
        atomicAdd(lossAcc, dterm);
        __threadfence();
        unsigned int old = atomicAdd(lossCnt, 1u);
        if (old == BATCH - 1) {
            double total = atomicAdd(lossAcc, 0.0);       // fresh read
            double msq = total / (double)(BATCH * PLEN * EMB);
            out[LOSS_OFF] = (float)(0.5 * msq);           // 0.4*e + 0.1*q, e==q numerically
        }
    }
    __syncthreads();
    int idx = sidx;
    const float4* src = (const float4*)(p + (size_t)idx * LD);
    float4* ek = (float4*)out;
    float4* ev = (float4*)(out + EK_FLOATS);
    for (int j = threadIdx.x; j < LD / 4; j += 256) {     // 1536 float4
        float4 v = src[j];
        int l = j / (EMB / 4);        // prompt-slot 0..7
        int r = j % (EMB / 4);
        if (l < 4) ek[b * EMB + l * (EMB / 4) + r] = v;
        else       ev[b * EMB + (l - 4) * (EMB / 4) + r] = v;
    }
}

extern "C" void kernel_launch(void* const* d_in, const int* in_sizes, int n_in,
                              void* d_out, int out_size, void* d_ws, size_t ws_size,
                              hipStream_t stream) {
    const float* xq = (const float*)d_in[0];
    // d_in[1] = l (always 0, in E_LAYERS)
    const float* xb = (const float*)d_in[2];
    const float* K  = (const float*)d_in[3];
    const float* p  = (const float*)d_in[4];
    float* out = (float*)d_out;

    double* G        = (double*)d_ws;          // 100*100 doubles = 80 KB
    double* cosm     = G + POOL * POOL;        // 256*100 doubles = 200 KB
    double* lossAcc  = cosm + BATCH * POOL;    // 1 double
    unsigned int* lossCnt = (unsigned int*)(lossAcc + 1);

    k1<<<GRID1, 256, 0, stream>>>(p, xq, K, xb, out, G, cosm, lossAcc, lossCnt);
    k2<<<GRID2, 256, 0, stream>>>(cosm, G, p, xb, out, lossAcc, lossCnt);
}

// Round 15
// 70.746 us; speedup vs baseline: 1.1223x; 1.1223x over previous
//
#include <hip/hip_runtime.h>

#define POOL 100
#define PLEN 8
#define EMB 768
#define KEYD 768
#define BATCH 256
#define LD (PLEN*EMB)              // 6144
#define EK_FLOATS (BATCH*4*EMB)    // 786432
#define XB_FLOATS (BATCH*197*EMB)  // 38756352
#define LOSS_OFF (2*EK_FLOATS)     // 1572864
#define XB_OFF (LOSS_OFF+1)        // 1572865 (4B-aligned only!)
#define NGT 325                    // 25*26/2 triangular 4x4 gram tiles
#define NCOS (BATCH*25)            // 6400 cos units
#define NPREP (NGT+NCOS)           // 6725 prep units
#define N4 9689087                 // (XB_FLOATS-3)/4 float4 in bulk copy
#define TILE 2048                  // float4 per copy block
#define NTILES 4731                // ceil(N4/TILE); tile 4730 partial
#define NSG 421                    // supergroups in kernel1
#define COPY_A (NSG*8)             // 3368 tiles in kernel1
#define COPY_B (NTILES-COPY_A)     // 1363 tiles in kernel2
#define GRID1 (NSG*24)             // 10104: rank<8 copy, rank>=8 prep
#define GRID2 (BATCH+COPY_B)       // 1619

typedef float v4f __attribute__((ext_vector_type(4)));
typedef v4f v4f_u __attribute__((aligned(4)));   // 4B-aligned float4 view (tail only)

// --- R12 copy tile (best measured: 70.8us total): lane-contiguous slots,
// 8 aligned dwordx4 PLAIN loads in flight (L3 absorbs ~half the read traffic;
// NT loads measurably hurt, R14), 8 shfl_up stitches, one divergent lane-0
// fixup, 8 NONTEMPORAL stores (no write-allocate; plain stores hurt, R13).
__device__ __forceinline__ void copy_tile(const float* __restrict__ xb,
                                          float* __restrict__ out, int tile) {
    const v4f* src4 = (const v4f*)xb;                // 16B aligned
    v4f* dst = (v4f*)(out + XB_OFF + 3);             // 16B aligned
    size_t base = (size_t)tile * TILE + threadIdx.x;
    int lane = threadIdx.x & 63;
    if (base + 7 * 256 < N4) {                       // full tile
        v4f v[8];
        #pragma unroll
        for (int k = 0; k < 8; ++k) v[k] = src4[base + (size_t)k * 256 + 1];
        float pw[8];
        #pragma unroll
        for (int k = 0; k < 8; ++k) pw[k] = __shfl_up(v[k][3], 1, 64);
        if (lane == 0) {                             // one divergent region
            #pragma unroll
            for (int k = 0; k < 8; ++k) pw[k] = xb[4 * (base + (size_t)k * 256) + 3];
        }
        #pragma unroll
        for (int k = 0; k < 8; ++k) {
            v4f o = {pw[k], v[k][0], v[k][1], v[k][2]};
            __builtin_nontemporal_store(o, &dst[base + (size_t)k * 256]);
        }
    } else {                                         // tail tile: misaligned fallback
        const v4f_u* srcu = (const v4f_u*)(xb + 3);
        #pragma unroll
        for (int k = 0; k < 8; ++k) {
            size_t j = base + (size_t)k * 256;
            if (j < N4) dst[j] = srcu[j];
        }
    }
}

// 4x4 row-group gram tile: block computes G[4gy+i][4gx+j] for i,j in 0..3.
__device__ __forceinline__ void gram_tile(const float* __restrict__ p,
                                          double* __restrict__ G, int t) {
    int gx = (int)((sqrt(8.0 * t + 1.0) - 1.0) * 0.5);
    while ((gx + 1) * (gx + 2) / 2 <= t) ++gx;
    while (gx * (gx + 1) / 2 > t) --gx;
    int gy = t - gx * (gx + 1) / 2;
    const v4f* P4 = (const v4f*)p;
    double acc[16];
    #pragma unroll
    for (int i = 0; i < 16; ++i) acc[i] = 0.0;
    #pragma unroll
    for (int ch = 0; ch < 6; ++ch) {                 // 1536 float4 cols / 256 thr
        int col = ch * 256 + threadIdx.x;
        v4f ay[4], ax[4];
        #pragma unroll
        for (int i = 0; i < 4; ++i) ay[i] = P4[(size_t)(4*gy + i) * 1536 + col];
        #pragma unroll
        for (int j = 0; j < 4; ++j) ax[j] = P4[(size_t)(4*gx + j) * 1536 + col];
        #pragma unroll
        for (int i = 0; i < 4; ++i)
            #pragma unroll
            for (int j = 0; j < 4; ++j)
                acc[i*4+j] += (double)ay[i][0]*ax[j][0] + (double)ay[i][1]*ax[j][1]
                            + (double)ay[i][2]*ax[j][2] + (double)ay[i][3]*ax[j][3];
    }
    #pragma unroll
    for (int i = 0; i < 16; ++i)
        for (int off = 32; off > 0; off >>= 1)
            acc[i] += __shfl_down(acc[i], off, 64);
    __shared__ double sg[4][16];
    int lane = threadIdx.x & 63, w = threadIdx.x >> 6;
    if (lane == 0) {
        #pragma unroll
        for (int i = 0; i < 16; ++i) sg[w][i] = acc[i];
    }
    __syncthreads();
    if (threadIdx.x < 16) {
        double v = sg[0][threadIdx.x] + sg[1][threadIdx.x]
                 + sg[2][threadIdx.x] + sg[3][threadIdx.x];
        int i = threadIdx.x >> 2, j = threadIdx.x & 3;
        int r = 4*gy + i, c = 4*gx + j;
        G[r * POOL + c] = v;
        G[c * POOL + r] = v;
    }
}

// cos[b,k] = <xq[b],K[k]> / max(||K[k]||,1e-12), one wave per (b,k).
__device__ __forceinline__ void cos_unit(const float* __restrict__ xq,
                                         const float* __restrict__ K,
                                         double* __restrict__ cosm, int c) {
    int b = c / 25, kg = c % 25;
    int w = threadIdx.x >> 6, lane = threadIdx.x & 63;
    int k = kg * 4 + w;
    const v4f* kr = (const v4f*)(K + (size_t)k * KEYD);
    const v4f* xr = (const v4f*)(xq + (size_t)b * KEYD);
    double dot = 0.0, sq = 0.0;
    #pragma unroll
    for (int it = 0; it < 3; ++it) {
        v4f a = kr[it * 64 + lane];
        v4f x = xr[it * 64 + lane];
        dot += (double)a[0]*x[0] + (double)a[1]*x[1] + (double)a[2]*x[2] + (double)a[3]*x[3];
        sq  += (double)a[0]*a[0] + (double)a[1]*a[1] + (double)a[2]*a[2] + (double)a[3]*a[3];
    }
    for (int off = 32; off > 0; off >>= 1) {
        dot += __shfl_down(dot, off, 64);
        sq  += __shfl_down(sq,  off, 64);
    }
    if (lane == 0)
        cosm[(size_t)b * POOL + k] = dot / fmax(sqrt(sq), 1e-12);
}

// Kernel 1: XCD-safe interleave of copy chunk A with ALL prep work.
// Supergroup = 24 consecutive blocks: ranks 0-7 copy (one per XCD per group),
// ranks 8-23 prep. Prep hides under copy BW.
__global__ void k1(const float* __restrict__ p, const float* __restrict__ xq,
                   const float* __restrict__ K, const float* __restrict__ xb,
                   float* __restrict__ out, double* __restrict__ G,
                   double* __restrict__ cosm, double* __restrict__ lossAcc,
                   unsigned int* __restrict__ lossCnt) {
    int b = blockIdx.x;
    int g = b / 24, r = b % 24;
    if (r < 8) {                                     // copy lane
        int tile = g * 8 + r;                        // 0..COPY_A-1, exact fit
        if (tile == 0) {
            if (threadIdx.x == 64) { lossAcc[0] = 0.0; lossCnt[0] = 0u; }
            if (threadIdx.x == 65) {
                out[XB_OFF]     = xb[0];
                out[XB_OFF + 1] = xb[1];
                out[XB_OFF + 2] = xb[2];
                out[XB_OFF + XB_FLOATS - 1] = xb[XB_FLOATS - 1];
            }
        }
        copy_tile(xb, out, tile);
        return;
    }
    int u = g * 16 + (r - 8);                        // prep unit 0..6735
    if (u < NGT)        gram_tile(p, G, u);
    else if (u < NPREP) cos_unit(xq, K, cosm, u - NGT);
    // else: 11 pad blocks
}

// Kernel 2: blocks [0,BATCH) = per-b vq (hidden under copy); rest = copy chunk B.
__global__ void k2(const double* __restrict__ cosm, const double* __restrict__ G,
                   const float* __restrict__ p, const float* __restrict__ xb,
                   float* __restrict__ out, double* __restrict__ lossAcc,
                   unsigned int* __restrict__ lossCnt) {
    if (blockIdx.x >= BATCH) {
        copy_tile(xb, out, COPY_A + (int)(blockIdx.x - BATCH));
        return;
    }
    int b = blockIdx.x;
    __shared__ double sa[POOL], sm[POOL];
    __shared__ double sred[4];
    __shared__ int sidx;
    int lane = threadIdx.x & 63, w = threadIdx.x >> 6;

    double cv = (threadIdx.x < POOL) ? cosm[(size_t)b * POOL + threadIdx.x] : -1.0e300;
    double m = cv;                                   // block max
    for (int off = 32; off > 0; off >>= 1) m = fmax(m, __shfl_down(m, off, 64));
    if (lane == 0) sred[w] = m;
    __syncthreads();
    m = fmax(fmax(sred[0], sred[1]), fmax(sred[2], sred[3]));
    __syncthreads();
    double e = (threadIdx.x < POOL) ? exp(cv - m) : 0.0;
    double ssum = e;                                 // block sum
    for (int off = 32; off > 0; off >>= 1) ssum += __shfl_down(ssum, off, 64);
    if (lane == 0) sred[w] = ssum;
    __syncthreads();
    ssum = sred[0] + sred[1] + sred[2] + sred[3];
    __syncthreads();
    if (threadIdx.x < POOL) sa[threadIdx.x] = e / ssum;   // alpha
    __syncthreads();
    double c = 0.0, paterm = 0.0;
    if (threadIdx.x < POOL) {
        #pragma unroll 4
        for (int k = 0; k < POOL; ++k)
            c += sa[k] * G[k * POOL + threadIdx.x];       // coalesced over tid
        paterm = sa[threadIdx.x] * c;
        sm[threadIdx.x] = G[threadIdx.x * POOL + threadIdx.x] - 2.0 * c;
    }
    double pa = paterm;                               // pa_sq block sum
    for (int off = 32; off > 0; off >>= 1) pa += __shfl_down(pa, off, 64);
    if (lane == 0) sred[w] = pa;
    __syncthreads();                                  // also fences sm[]
    pa = sred[0] + sred[1] + sred[2] + sred[3];
    if (threadIdx.x == 0) {
        int best = 0; double bm = sm[0];
        for (int k = 1; k < POOL; ++k)
            if (sm[k] < bm) { bm = sm[k]; best = k; }     // first-index tiebreak = np.argmin
        sidx = best;
        double dterm = pa + bm;    // = pa_sq - 2*cross[idx] + pp_sq[idx]
        atomicAdd(lossAcc, dterm);
        __threadfence();
        unsigned int old = atomicAdd(lossCnt, 1u);
        if (old == BATCH - 1) {
            double total = atomicAdd(lossAcc, 0.0);       // fresh read
            double msq = total / (double)(BATCH * PLEN * EMB);
            out[LOSS_OFF] = (float)(0.5 * msq);           // 0.4*e + 0.1*q, e==q numerically
        }
    }
    __syncthreads();
    int idx = sidx;
    const float4* src = (const float4*)(p + (size_t)idx * LD);
    float4* ek = (float4*)out;
    float4* ev = (float4*)(out + EK_FLOATS);
    for (int j = threadIdx.x; j < LD / 4; j += 256) {     // 1536 float4
        float4 v = src[j];
        int l = j / (EMB / 4);        // prompt-slot 0..7
        int r = j % (EMB / 4);
        if (l < 4) ek[b * EMB + l * (EMB / 4) + r] = v;
        else       ev[b * EMB + (l - 4) * (EMB / 4) + r] = v;
    }
}

extern "C" void kernel_launch(void* const* d_in, const int* in_sizes, int n_in,
                              void* d_out, int out_size, void* d_ws, size_t ws_size,
                              hipStream_t stream) {
    const float* xq = (const float*)d_in[0];
    // d_in[1] = l (always 0, in E_LAYERS)
    const float* xb = (const float*)d_in[2];
    const float* K  = (const float*)d_in[3];
    const float* p  = (const float*)d_in[4];
    float* out = (float*)d_out;

    double* G        = (double*)d_ws;          // 100*100 doubles = 80 KB
    double* cosm     = G + POOL * POOL;        // 256*100 doubles = 200 KB
    double* lossAcc  = cosm + BATCH * POOL;    // 1 double
    unsigned int* lossCnt = (unsigned int*)(lossAcc + 1);

    k1<<<GRID1, 256, 0, stream>>>(p, xq, K, xb, out, G, cosm, lossAcc, lossCnt);
    k2<<<GRID2, 256, 0, stream>>>(cosm, G, p, xb, out, lossAcc, lossCnt);
}